// Round 7
// baseline (249.143 us; speedup 1.0000x reference)
//
#include <hip/hip_runtime.h>
#include <hip/hip_bf16.h>

#define T 50
#define NB 64
#define NS 512
#define START_TAG 48
#define STOP_TAG 49
#define PITCH 88       // halfword pitch: 176 B rows -> 16B-aligned rows, uniform bank spread

typedef _Float16 f16_t;
typedef _Float16 f16x2 __attribute__((ext_vector_type(2)));
typedef _Float16 f16x4 __attribute__((ext_vector_type(4)));
typedef _Float16 f16x8 __attribute__((ext_vector_type(8)));
typedef float    f32x4 __attribute__((ext_vector_type(4)));

static constexpr float LOG2E = 1.4426950408889634f;
static constexpr float LN2F  = 0.6931471805599453f;
static constexpr float S_E   = 6.0f;     // static log2 shift folded out of E
#define NEG_BIG (-1.0e38f)

__device__ __forceinline__ float fexp2(float x) { return __builtin_amdgcn_exp2f(x); }
__device__ __forceinline__ float flog2(float x) { return __builtin_amdgcn_logf(x); }
__device__ __forceinline__ f16x2 bcast_h2(f16x2 v, int src) {
    unsigned u = __builtin_amdgcn_readlane(__builtin_bit_cast(unsigned, v), src);
    return __builtin_bit_cast(f16x2, u);
}
__device__ __forceinline__ f16x2 pack_h2(float a, float b) {
    return __builtin_bit_cast(f16x2, __builtin_amdgcn_cvt_pkrtz(a, b));
}

// Full-wave (64-lane) fmax via DPP (VALU pipe) -> uniform value via lane 63.
__device__ __forceinline__ float wave_fmax_dpp(float x) {
#define DPP_STEP(ctrl)                                                        \
    do {                                                                      \
        int _s = __builtin_bit_cast(int, x);                                  \
        int _p = __builtin_amdgcn_update_dpp(_s, _s, (ctrl), 0xf, 0xf, false);\
        x = fmaxf(x, __builtin_bit_cast(float, _p));                          \
    } while (0)
    DPP_STEP(0x111);  // row_shr:1
    DPP_STEP(0x112);  // row_shr:2
    DPP_STEP(0x114);  // row_shr:4
    DPP_STEP(0x118);  // row_shr:8
    DPP_STEP(0x142);  // row_bcast:15
    DPP_STEP(0x143);  // row_bcast:31
#undef DPP_STEP
    return __builtin_bit_cast(float,
        __builtin_amdgcn_readlane(__builtin_bit_cast(int, x), 63));
}

// =====================================================================
// FUSED kernel: phase 1 (all NCHT*NB blocks) = chunk products; then a
// device-scope fence + atomic counter; blocks with c==0 spin (bounded)
// until all blocks signal, then run phase 2 (combine) for their batch.
// Spin is deadlock-free without co-residency assumptions: spinners only
// wait on blocks that run to completion. Counter is re-zeroed by a 4-B
// memset each launch; `out` is zeroed in-kernel by block (0,0) before
// its fence+signal (counter full => zero visible).
//
// Chunk phase (vs round 6):
//  - __launch_bounds__(256,4): 128 VGPRs/wave -> Efrag/acc in VGPRs,
//    no per-step v_accvgpr shuffling (round 6 was squeezed to 48 VGPRs).
//  - renorm DELAYED 2 steps: descale uses max from s-2 (any pow2 is
//    mathematically exact - D compensates; only f16 range matters, and
//    per-step growth ~2^±7 keeps values far from 2^16). DPP chain is
//    off the dependency path.
//  - PITCH 88: rows 176 B -> 16B-aligned (1x ds_read_b128 per A half),
//    uniform bank distribution on reads and writes (PITCH 72 had 4-way
//    write aliasing: bank-conflict counter tripled in rounds 4/6).
// =====================================================================
template<int NCHT, int CHLT>
__global__ __launch_bounds__(256, 4)
void crf_fused(const float* __restrict__ feats, const int* __restrict__ mask,
               const int* __restrict__ tags, const float* __restrict__ trans,
               f16_t* __restrict__ wsCt, float* __restrict__ wsD,
               int* __restrict__ cnt, float* __restrict__ out, int out_size) {
    const int c    = blockIdx.x;          // chunk
    const int b    = blockIdx.y;          // batch
    const int tid  = threadIdx.x;
    const int w    = tid >> 6;
    const int lane = tid & 63;
    const int l15  = lane & 15;
    const int q    = lane >> 4;

    __shared__ f16_t sC[64 * PITCH];      // 4 private 16-row stripes
    __shared__ float sF[CHLT][64];        // 2^(f_t*log2e) per step/col
    __shared__ float sGold;               // combine-phase handoff

    const int t0  = c * CHLT + 1;
    const int nst = NS - t0 < CHLT ? NS - t0 : CHLT;

    // ---- E fragments, column-permuted (slot n=16*c2+l15 -> col 4*l15+c2)
    f16x8 Efrag[2][4];
    #pragma unroll
    for (int kb = 0; kb < 2; kb++)
        #pragma unroll
        for (int c2 = 0; c2 < 4; c2++) {
            f16x8 v;
            const int j = 4 * l15 + c2;
            #pragma unroll
            for (int jj = 0; jj < 8; jj++) {
                int kk = 32 * kb + q * 8 + jj;
                float x = 0.f;
                if (kk < T && j < T) x = fexp2(fmaf(trans[kk * T + j], LOG2E, -S_E));
                v[jj] = (f16_t)x;
            }
            Efrag[kb][c2] = v;
        }

    // ---- bulk preload: feats block (exp2 once)
    for (int r = w; r < CHLT; r += 4) {
        int tl = t0 + r; tl = tl < NS ? tl : NS - 1;
        float fv = (lane < T && r < nst) ? feats[((size_t)b * NS + tl) * T + lane] : 0.f;
        sF[r][lane] = (lane < T && r < nst) ? fexp2(fv * LOG2E) : 0.f;
    }

    // ---- mask bitmap (one ballot; per-step test is SALU)
    unsigned long long bm;
    {
        int tl = t0 + lane; tl = tl < NS ? tl : NS - 1;
        int mv = (lane < nst) ? mask[b * NS + tl] : 0;
        bm = __ballot(mv != 0);
    }

    // ---- init: C = I
    for (int idx = tid; idx < 64 * PITCH; idx += 256) sC[idx] = (f16_t)0.f;
    if (tid < 64) sC[tid * PITCH + tid] = (f16_t)1.f;
    __syncthreads();

    float D  = 0.f;
    float m1 = 1.f, m2 = 1.f;             // wave max from s-1, s-2 (delayed renorm)
    const int abase  = (16 * w + l15) * PITCH + 8 * q;
    const int sbase0 = (16 * w + 4 * q) * PITCH + 4 * l15;

    for (int s = 0; s < nst; s++) {
        if ((bm >> s) & 1ull) {
            // descale from the max TWO doit-steps back (off critical path;
            // exact pow2, D compensates -> correctness holds for any value)
            int ebits = (int)((__float_as_uint(m2) >> 23) & 255) - 127;
            ebits = ebits > 14 ? 14 : (ebits < -14 ? -14 : ebits);
            const float descale = __uint_as_float((unsigned)(127 - ebits) << 23);
            D += (float)ebits + S_E;

            f32x4 csv = *(const f32x4*)&sF[s][4 * l15];
            f16x8 A0  = *(const f16x8*)&sC[abase];
            f16x8 A1  = *(const f16x8*)&sC[abase + 32];

            f32x4 acc[4];
            #pragma unroll
            for (int c2 = 0; c2 < 4; c2++) {
                acc[c2] = __builtin_amdgcn_mfma_f32_16x16x32_f16(A0, Efrag[0][c2],
                                                                 (f32x4){0.f,0.f,0.f,0.f}, 0, 0, 0);
                acc[c2] = __builtin_amdgcn_mfma_f32_16x16x32_f16(A1, Efrag[1][c2],
                                                                 acc[c2], 0, 0, 0);
            }

            f32x4 cs2;
            #pragma unroll
            for (int c2 = 0; c2 < 4; c2++) cs2[c2] = csv[c2] * descale;

            float wmax = 0.f;
            #pragma unroll
            for (int r = 0; r < 4; r++) {
                f16x4 hv;
                #pragma unroll
                for (int c2 = 0; c2 < 4; c2++) {
                    float v = acc[c2][r] * cs2[c2];
                    wmax = fmaxf(wmax, v);
                    hv[c2] = (f16_t)v;     // RNE
                }
                *(f16x4*)&sC[sbase0 + r * PITCH] = hv;
            }

            m2 = m1;
            m1 = wave_fmax_dpp(wmax);      // consumed two steps later
        }
    }

    __syncthreads();                      // epilogue reads all stripes

    // ---- store C TRANSPOSED: wsCt[.. + col*64 + row] = C[row][col]
    {
        const int col = tid >> 2;
        const int r0  = (tid & 3) << 4;
        unsigned short tmp[16];
        #pragma unroll
        for (int r = 0; r < 16; r++)
            tmp[r] = __builtin_bit_cast(unsigned short, sC[(r0 + r) * PITCH + col]);
        f16_t* dst = wsCt + ((size_t)(b * NCHT + c)) * 4096 + col * 64 + r0;
        ((int4*)dst)[0] = *(const int4*)&tmp[0];
        ((int4*)dst)[1] = *(const int4*)&tmp[8];
    }
    if (lane == 0) wsD[(b * NCHT + c) * 4 + w] = D;   // per-wave shift
    if (c == 0 && b == 0)
        for (int i = tid; i < out_size; i += 256) out[i] = 0.f;

    // ---- publish + signal ----
    __threadfence();                      // device scope: wsCt/wsD/out visible
    __syncthreads();
    if (tid == 0) (void)atomicAdd(cnt, 1);
    if (c != 0) return;

    // ---- wait for all blocks (bounded spin; spinners wait only on
    //      blocks that run to completion -> no residency assumption) ----
    if (tid == 0) {
        int it = 0;
        while (atomicAdd(cnt, 0) < NCHT * NB && it < 2000000) {
            __builtin_amdgcn_s_sleep(2);
            ++it;
        }
    }
    __syncthreads();
    __threadfence();                      // acquire side

    // =========== combine phase (block (0,b)): wave0 part-chain, wave1 gold ===========
    const int wv = tid >> 6;
    float fwd = 0.f;

    if (wv == 1) {
        float gsum = 0.f;
        int   lcnt = 0;
        for (int s = lane; s < NS; s += 64) {
            int   m  = mask[b * NS + s];
            int   tg = tags[b * NS + s];
            int   pv = (s == 0) ? START_TAG : tags[b * NS + s - 1];
            float e  = feats[((size_t)b * NS + s) * T + tg];
            float tr = trans[pv * T + tg];
            if (m) { gsum += e + tr; lcnt += 1; }
        }
        #pragma unroll
        for (int off = 32; off > 0; off >>= 1) {
            gsum += __shfl_down(gsum, off, 64);
            lcnt += __shfl_down(lcnt, off, 64);
        }
        if (lane == 0) sGold = gsum + trans[tags[b * NS + lcnt - 1] * T + STOP_TAG];
    } else if (wv == 0) {
        float part = (lane < T)
            ? (feats[(size_t)b * NS * T + lane] + trans[START_TAG * T + lane]) * LOG2E
            : NEG_BIG;

        float Dq[NCHT];
        #pragma unroll
        for (int cc = 0; cc < NCHT; cc++)
            Dq[cc] = wsD[(b * NCHT + cc) * 4 + (lane >> 4)];

        int cur[32], nxt[32];
        {
            const f16_t* src = wsCt + (size_t)b * NCHT * 4096 + lane * 64;
            #pragma unroll
            for (int kk = 0; kk < 8; kk++)
                *(int4*)&cur[4 * kk] = ((const int4*)src)[kk];
        }

        #pragma unroll
        for (int cc = 0; cc < NCHT; cc++) {
            if (cc + 1 < NCHT) {
                const f16_t* src = wsCt + (size_t)(b * NCHT + cc + 1) * 4096 + lane * 64;
                #pragma unroll
                for (int kk = 0; kk < 8; kk++)
                    *(int4*)&nxt[4 * kk] = ((const int4*)src)[kk];
            }

            float tmp = part + Dq[cc];
            float sft = wave_fmax_dpp(tmp);
            float ex  = fexp2(tmp - sft);
            float exo = __shfl_xor(ex, 1, 64);
            f16x2 pk  = pack_h2(ex, exo);

            float a0 = 0.f, a1 = 0.f, a2 = 0.f, a3 = 0.f;
            #pragma unroll
            for (int k = 0; k < 25; k += 4) {
                a0 = __builtin_amdgcn_fdot2(bcast_h2(pk, 2 * k), __builtin_bit_cast(f16x2, cur[k]), a0, false);
                if (k + 1 < 25) a1 = __builtin_amdgcn_fdot2(bcast_h2(pk, 2 * (k + 1)), __builtin_bit_cast(f16x2, cur[k + 1]), a1, false);
                if (k + 2 < 25) a2 = __builtin_amdgcn_fdot2(bcast_h2(pk, 2 * (k + 2)), __builtin_bit_cast(f16x2, cur[k + 2]), a2, false);
                if (k + 3 < 25) a3 = __builtin_amdgcn_fdot2(bcast_h2(pk, 2 * (k + 3)), __builtin_bit_cast(f16x2, cur[k + 3]), a3, false);
            }
            part = sft + flog2((a0 + a1) + (a2 + a3));

            if (cc + 1 < NCHT) {
                #pragma unroll
                for (int kk = 0; kk < 32; kk++) cur[kk] = nxt[kk];
            }
        }

        float v = (lane < T) ? part + trans[lane * T + STOP_TAG] * LOG2E : NEG_BIG;
        float mx = wave_fmax_dpp(v);
        float ee = (lane < T) ? fexp2(v - mx) : 0.f;
        #pragma unroll
        for (int off = 32; off > 0; off >>= 1) ee += __shfl_xor(ee, off, 64);
        fwd = (mx + flog2(ee)) * LN2F;
    }

    __syncthreads();
    if (tid == 0) atomicAdd(out, fwd - sGold);
}

extern "C" void kernel_launch(void* const* d_in, const int* in_sizes, int n_in,
                              void* d_out, int out_size, void* d_ws, size_t ws_size,
                              hipStream_t stream) {
    const float* feats = (const float*)d_in[0];
    const int*   mask  = (const int*)d_in[1];
    const int*   tags  = (const int*)d_in[2];
    const float* trans = (const float*)d_in[3];
    float* out = (float*)d_out;

    const size_t matBytes16 = (size_t)NB * 16 * 4096 * sizeof(f16_t);
    const size_t dBytes16   = (size_t)NB * 16 * 4 * sizeof(float);
    const size_t need16     = matBytes16 + dBytes16 + sizeof(int);

    if (ws_size >= need16) {
        f16_t* wsCt = (f16_t*)d_ws;
        float* wsD  = (float*)((char*)d_ws + matBytes16);
        int*   cnt  = (int*)((char*)d_ws + matBytes16 + dBytes16);
        (void)hipMemsetAsync(cnt, 0, sizeof(int), stream);
        crf_fused<16, 32><<<dim3(16, NB), 256, 0, stream>>>(
            feats, mask, tags, trans, wsCt, wsD, cnt, out, out_size);
    } else {
        const size_t matBytes8 = (size_t)NB * 8 * 4096 * sizeof(f16_t);
        const size_t dBytes8   = (size_t)NB * 8 * 4 * sizeof(float);
        f16_t* wsCt = (f16_t*)d_ws;
        float* wsD  = (float*)((char*)d_ws + matBytes8);
        int*   cnt  = (int*)((char*)d_ws + matBytes8 + dBytes8);
        (void)hipMemsetAsync(cnt, 0, sizeof(int), stream);
        crf_fused<8, 64><<<dim3(8, NB), 256, 0, stream>>>(
            feats, mask, tags, trans, wsCt, wsD, cnt, out, out_size);
    }
}

// Round 8
// 134.052 us; speedup vs baseline: 1.8586x; 1.8586x over previous
//
#include <hip/hip_runtime.h>
#include <hip/hip_bf16.h>

#define T 50
#define NB 64
#define NS 512
#define START_TAG 48
#define STOP_TAG 49

typedef _Float16 f16_t;
typedef _Float16 f16x2 __attribute__((ext_vector_type(2)));
typedef _Float16 f16x4 __attribute__((ext_vector_type(4)));
typedef float    f32x4 __attribute__((ext_vector_type(4)));

static constexpr float LOG2E = 1.4426950408889634f;
static constexpr float LN2F  = 0.6931471805599453f;
static constexpr float S_E   = 6.0f;     // static log2 shift folded out of E
#define NEG_BIG (-1.0e38f)

__device__ __forceinline__ float fexp2(float x) { return __builtin_amdgcn_exp2f(x); }
__device__ __forceinline__ float flog2(float x) { return __builtin_amdgcn_logf(x); }
__device__ __forceinline__ f16x2 bcast_h2(f16x2 v, int src) {
    unsigned u = __builtin_amdgcn_readlane(__builtin_bit_cast(unsigned, v), src);
    return __builtin_bit_cast(f16x2, u);
}
__device__ __forceinline__ f16x2 pack_h2(float a, float b) {
    return __builtin_bit_cast(f16x2, __builtin_amdgcn_cvt_pkrtz(a, b));
}

// Full-wave (64-lane) fmax via DPP (VALU pipe) -> uniform value via lane 63.
__device__ __forceinline__ float wave_fmax_dpp(float x) {
#define DPP_STEP(ctrl)                                                        \
    do {                                                                      \
        int _s = __builtin_bit_cast(int, x);                                  \
        int _p = __builtin_amdgcn_update_dpp(_s, _s, (ctrl), 0xf, 0xf, false);\
        x = fmaxf(x, __builtin_bit_cast(float, _p));                          \
    } while (0)
    DPP_STEP(0x111);  // row_shr:1
    DPP_STEP(0x112);  // row_shr:2
    DPP_STEP(0x114);  // row_shr:4
    DPP_STEP(0x118);  // row_shr:8
    DPP_STEP(0x142);  // row_bcast:15
    DPP_STEP(0x143);  // row_bcast:31
#undef DPP_STEP
    return __builtin_bit_cast(float,
        __builtin_amdgcn_readlane(__builtin_bit_cast(int, x), 63));
}

// =====================================================================
// Kernel 1 (register-resident, zero LDS per step): ONE WAVE per
// (batch, chunk). Maintain M = C^T; step: M' = D_s * (E^T * M), i.e.
// C' = C*(E*D_s) transposed. KEY: with v_mfma_f32_16x16x16f16 the
// D-output fragment layout (col=lane&15, rows 4q+reg) EQUALS the
// B-operand layout (col=lane&15, k rows 4q+j) -> the MFMA output feeds
// the next step's B operand directly in registers. No LDS round-trip,
// no barriers, no inter-wave traffic.
//  - M: 16 tiles (kb,nb) of f16x4 = 32 VGPRs.  E^T: 16 const tiles.
//  - per step: 64 MFMAs (4 mb x 4 nb x 4 kb chained), row-scale by
//    cs[row]*descale in f32, RNE f16 (same numerics as prior rounds).
//  - renorm: per-wave max (tree + DPP), DELAYED 2 steps (exact pow2,
//    D compensates), SALU descale.
//  - cs via 4x ds_read_b128 from preloaded sF (only per-step LDS).
//  - epilogue: LDS transpose (reuses sF space) -> wsCt row j = M[j][:]
//    (coalesced 128 B per lane), D uniform per chunk.
// =====================================================================
template<int NCHT, int CHLT>
__global__ __launch_bounds__(64, 1)
void crf_chunk(const float* __restrict__ feats, const int* __restrict__ mask,
               const float* __restrict__ trans, f16_t* __restrict__ wsCt,
               float* __restrict__ wsD) {
    const int c    = blockIdx.x;          // chunk
    const int b    = blockIdx.y;          // batch
    const int lane = threadIdx.x;
    const int l15  = lane & 15;
    const int q    = lane >> 4;

    constexpr int SF_BYTES = CHLT * 64 * 4;
    constexpr int TR_BYTES = 64 * 66 * 2;
    __shared__ unsigned char smem[SF_BYTES > TR_BYTES ? SF_BYTES : TR_BYTES];
    float (*sF)[64] = (float (*)[64])smem;

    const int t0  = c * CHLT + 1;
    const int nst = (NS - t0 < CHLT) ? (NS - t0) : CHLT;

    // ---- A-const: E^T tiles. A(mb,kb) elem j = E[16kb+4q+j][16mb+l15]
    f16x4 Afrag[4][4];
    #pragma unroll
    for (int mb = 0; mb < 4; mb++)
        #pragma unroll
        for (int kb = 0; kb < 4; kb++) {
            f16x4 v;
            #pragma unroll
            for (int j = 0; j < 4; j++) {
                const int kk = 16 * kb + 4 * q + j;   // row of E
                const int mm = 16 * mb + l15;         // col of E
                float x = 0.f;
                if (kk < T && mm < T) x = fexp2(fmaf(trans[kk * T + mm], LOG2E, -S_E));
                v[j] = (f16_t)x;
            }
            Afrag[mb][kb] = v;
        }

    // ---- preload sF (exp2 once), single wave
    #pragma unroll 4
    for (int r = 0; r < CHLT; r++) {
        int tl = t0 + r; tl = tl < NS ? tl : NS - 1;
        float fv = (lane < T && r < nst) ? feats[((size_t)b * NS + tl) * T + lane] : 0.f;
        sF[r][lane] = (lane < T && r < nst) ? fexp2(fv * LOG2E) : 0.f;
    }

    // ---- mask bitmap (one ballot; per-step test is SALU)
    unsigned long long bm;
    {
        int tl = t0 + lane; tl = tl < NS ? tl : NS - 1;
        int mv = (lane < nst) ? mask[b * NS + tl] : 0;
        bm = __ballot(mv != 0);
    }

    // ---- init M = I: tile (kb,nb) elem j = (kb==nb && 4q+j==l15)
    f16x4 Bt[16];
    #pragma unroll
    for (int kb = 0; kb < 4; kb++)
        #pragma unroll
        for (int nb = 0; nb < 4; nb++) {
            f16x4 v;
            #pragma unroll
            for (int j = 0; j < 4; j++)
                v[j] = (f16_t)((kb == nb && 4 * q + j == l15) ? 1.f : 0.f);
            Bt[kb * 4 + nb] = v;
        }

    float D  = 0.f;
    float m1 = 1.f, m2 = 1.f;             // wave max from s-1, s-2 (delayed renorm)

    for (int s = 0; s < nst; s++) {
        if ((bm >> s) & 1ull) {
            // descale from the max TWO doit-steps back (exact pow2; D compensates)
            int ebits = (int)((__float_as_uint(m2) >> 23) & 255) - 127;
            ebits = ebits > 14 ? 14 : (ebits < -14 ? -14 : ebits);
            const float descale = __uint_as_float((unsigned)(127 - ebits) << 23);
            D += (float)ebits + S_E;

            // row scales: rows 16mb+4q..+3 -> f32x4 per mb (only per-step LDS)
            f32x4 cs[4];
            #pragma unroll
            for (int mb = 0; mb < 4; mb++) {
                f32x4 t = *(const f32x4*)&sF[s][16 * mb + 4 * q];
                #pragma unroll
                for (int r = 0; r < 4; r++) t[r] *= descale;
                cs[mb] = t;
            }

            float wm = 0.f;
            #pragma unroll
            for (int nb = 0; nb < 4; nb++) {
                f32x4 acc[4];
                #pragma unroll
                for (int mb = 0; mb < 4; mb++) acc[mb] = (f32x4){0.f, 0.f, 0.f, 0.f};
                #pragma unroll
                for (int kb = 0; kb < 4; kb++)
                    #pragma unroll
                    for (int mb = 0; mb < 4; mb++)
                        acc[mb] = __builtin_amdgcn_mfma_f32_16x16x16f16(
                            Afrag[mb][kb], Bt[kb * 4 + nb], acc[mb], 0, 0, 0);
                #pragma unroll
                for (int mb = 0; mb < 4; mb++) {
                    float v0 = acc[mb][0] * cs[mb][0];
                    float v1 = acc[mb][1] * cs[mb][1];
                    float v2 = acc[mb][2] * cs[mb][2];
                    float v3 = acc[mb][3] * cs[mb][3];
                    wm = fmaxf(wm, fmaxf(fmaxf(v0, v1), fmaxf(v2, v3)));
                    f16x4 hv;
                    hv[0] = (f16_t)v0; hv[1] = (f16_t)v1;   // RNE, matches prior rounds
                    hv[2] = (f16_t)v2; hv[3] = (f16_t)v3;
                    Bt[mb * 4 + nb] = hv;   // M' tile (mb,nb) -> next B(kb=mb,nb)
                }
            }

            m2 = m1;
            m1 = wave_fmax_dpp(wm);        // consumed two steps later
        }
    }

    // ---- epilogue: LDS transpose (reuse smem; sF dead), then coalesced store
    {
        f16_t* Ml = (f16_t*)smem;          // [64][66] row-major, pad 2
        const int P2 = 66;
        #pragma unroll
        for (int kb = 0; kb < 4; kb++)
            #pragma unroll
            for (int nb = 0; nb < 4; nb++) {
                f16x4 v = Bt[kb * 4 + nb];
                #pragma unroll
                for (int r = 0; r < 4; r++)
                    Ml[(16 * kb + 4 * q + r) * P2 + 16 * nb + l15] = v[r];
            }
        // same wave: LDS ops in-order; no barrier needed
        f16_t* dst = wsCt + ((size_t)(b * NCHT + c)) * 4096 + lane * 64;
        const f16_t* src = &Ml[lane * P2];
        #pragma unroll
        for (int i = 0; i < 8; i++)
            ((int4*)dst)[i] = *(const int4*)&src[8 * i];
    }
    if (lane == 0) wsD[b * NCHT + c] = D;
}

// =====================================================================
// Kernel 2: 2 waves per batch. Wave 0: part-chain over NCHT chunk
// matrices (lane j holds wsCt row j = column j of C, contiguous 128 B,
// prefetched one chunk ahead; true-max shift via DPP; packed-f16 dot2).
// Wave 1: gold score concurrently. D is uniform per chunk now.
// =====================================================================
template<int NCHT>
__global__ __launch_bounds__(128, 1)
void crf_combine(const float* __restrict__ feats, const int* __restrict__ mask,
                 const int* __restrict__ tags, const float* __restrict__ trans,
                 const f16_t* __restrict__ wsCt, const float* __restrict__ wsD,
                 float* __restrict__ out) {
    const int b    = blockIdx.x;
    const int tid  = threadIdx.x;
    const int wv   = tid >> 6;
    const int lane = tid & 63;

    __shared__ float sGold;
    float fwd = 0.f;

    if (wv == 1) {
        float gsum = 0.f;
        int   lcnt = 0;
        for (int s = lane; s < NS; s += 64) {
            int   m  = mask[b * NS + s];
            int   tg = tags[b * NS + s];
            int   pv = (s == 0) ? START_TAG : tags[b * NS + s - 1];
            float e  = feats[((size_t)b * NS + s) * T + tg];
            float tr = trans[pv * T + tg];
            if (m) { gsum += e + tr; lcnt += 1; }
        }
        #pragma unroll
        for (int off = 32; off > 0; off >>= 1) {
            gsum += __shfl_down(gsum, off, 64);
            lcnt += __shfl_down(lcnt, off, 64);
        }
        if (lane == 0) sGold = gsum + trans[tags[b * NS + lcnt - 1] * T + STOP_TAG];
    } else {
        float part = (lane < T)
            ? (feats[(size_t)b * NS * T + lane] + trans[START_TAG * T + lane]) * LOG2E
            : NEG_BIG;

        float Dq[NCHT];
        #pragma unroll
        for (int cc = 0; cc < NCHT; cc++) Dq[cc] = wsD[b * NCHT + cc];

        int cur[32], nxt[32];
        {
            const f16_t* src = wsCt + (size_t)b * NCHT * 4096 + lane * 64;
            #pragma unroll
            for (int kk = 0; kk < 8; kk++)
                *(int4*)&cur[4 * kk] = ((const int4*)src)[kk];
        }

        #pragma unroll
        for (int cc = 0; cc < NCHT; cc++) {
            if (cc + 1 < NCHT) {
                const f16_t* src = wsCt + (size_t)(b * NCHT + cc + 1) * 4096 + lane * 64;
                #pragma unroll
                for (int kk = 0; kk < 8; kk++)
                    *(int4*)&nxt[4 * kk] = ((const int4*)src)[kk];
            }

            float tmp = part + Dq[cc];
            float sft = wave_fmax_dpp(tmp);
            float ex  = fexp2(tmp - sft);
            float exo = __shfl_xor(ex, 1, 64);
            f16x2 pk  = pack_h2(ex, exo);

            float a0 = 0.f, a1 = 0.f, a2 = 0.f, a3 = 0.f;
            #pragma unroll
            for (int k = 0; k < 25; k += 4) {
                a0 = __builtin_amdgcn_fdot2(bcast_h2(pk, 2 * k), __builtin_bit_cast(f16x2, cur[k]), a0, false);
                if (k + 1 < 25) a1 = __builtin_amdgcn_fdot2(bcast_h2(pk, 2 * (k + 1)), __builtin_bit_cast(f16x2, cur[k + 1]), a1, false);
                if (k + 2 < 25) a2 = __builtin_amdgcn_fdot2(bcast_h2(pk, 2 * (k + 2)), __builtin_bit_cast(f16x2, cur[k + 2]), a2, false);
                if (k + 3 < 25) a3 = __builtin_amdgcn_fdot2(bcast_h2(pk, 2 * (k + 3)), __builtin_bit_cast(f16x2, cur[k + 3]), a3, false);
            }
            part = sft + flog2((a0 + a1) + (a2 + a3));

            if (cc + 1 < NCHT) {
                #pragma unroll
                for (int kk = 0; kk < 32; kk++) cur[kk] = nxt[kk];
            }
        }

        float v = (lane < T) ? part + trans[lane * T + STOP_TAG] * LOG2E : NEG_BIG;
        float mx = wave_fmax_dpp(v);
        float ee = (lane < T) ? fexp2(v - mx) : 0.f;
        #pragma unroll
        for (int off = 32; off > 0; off >>= 1) ee += __shfl_xor(ee, off, 64);
        fwd = (mx + flog2(ee)) * LN2F;
    }

    __syncthreads();
    if (tid == 0) atomicAdd(out, fwd - sGold);
}

extern "C" void kernel_launch(void* const* d_in, const int* in_sizes, int n_in,
                              void* d_out, int out_size, void* d_ws, size_t ws_size,
                              hipStream_t stream) {
    const float* feats = (const float*)d_in[0];
    const int*   mask  = (const int*)d_in[1];
    const int*   tags  = (const int*)d_in[2];
    const float* trans = (const float*)d_in[3];
    float* out = (float*)d_out;

    (void)hipMemsetAsync(out, 0, sizeof(float) * out_size, stream);

    const size_t matBytes16 = (size_t)NB * 16 * 4096 * sizeof(f16_t);
    const size_t need16     = matBytes16 + (size_t)NB * 16 * sizeof(float);

    if (ws_size >= need16) {
        // preferred: 16 chunks x 32 steps, 1024 single-wave blocks
        f16_t* wsCt = (f16_t*)d_ws;
        float* wsD  = (float*)((char*)d_ws + matBytes16);
        crf_chunk<16, 32><<<dim3(16, NB), 64, 0, stream>>>(feats, mask, trans, wsCt, wsD);
        crf_combine<16><<<NB, 128, 0, stream>>>(feats, mask, tags, trans, wsCt, wsD, out);
    } else {
        // fallback: 8 chunks x 64 steps (fits 4.2 MB)
        const size_t matBytes8 = (size_t)NB * 8 * 4096 * sizeof(f16_t);
        f16_t* wsCt = (f16_t*)d_ws;
        float* wsD  = (float*)((char*)d_ws + matBytes8);
        crf_chunk<8, 64><<<dim3(8, NB), 64, 0, stream>>>(feats, mask, trans, wsCt, wsD);
        crf_combine<8><<<NB, 128, 0, stream>>>(feats, mask, tags, trans, wsCt, wsD, out);
    }
}

// Round 9
// 107.162 us; speedup vs baseline: 2.3249x; 1.2509x over previous
//
#include <hip/hip_runtime.h>
#include <hip/hip_bf16.h>

#define T 50
#define NB 64
#define NS 512
#define START_TAG 48
#define STOP_TAG 49

typedef _Float16 f16_t;
typedef _Float16 f16x2 __attribute__((ext_vector_type(2)));
typedef _Float16 f16x4 __attribute__((ext_vector_type(4)));
typedef float    f32x4 __attribute__((ext_vector_type(4)));

static constexpr float LOG2E = 1.4426950408889634f;
static constexpr float LN2F  = 0.6931471805599453f;
static constexpr float S_E   = 6.0f;     // static log2 shift folded out of E
#define NEG_BIG (-1.0e38f)

__device__ __forceinline__ float fexp2(float x) { return __builtin_amdgcn_exp2f(x); }
__device__ __forceinline__ float flog2(float x) { return __builtin_amdgcn_logf(x); }
__device__ __forceinline__ f16x2 bcast_h2(f16x2 v, int src) {
    unsigned u = __builtin_amdgcn_readlane(__builtin_bit_cast(unsigned, v), src);
    return __builtin_bit_cast(f16x2, u);
}
__device__ __forceinline__ f16x2 pack_h2(float a, float b) {
    return __builtin_bit_cast(f16x2, __builtin_amdgcn_cvt_pkrtz(a, b));
}

// Full-wave (64-lane) fmax via DPP (VALU pipe) -> uniform value via lane 63.
__device__ __forceinline__ float wave_fmax_dpp(float x) {
#define DPP_STEP(ctrl)                                                        \
    do {                                                                      \
        int _s = __builtin_bit_cast(int, x);                                  \
        int _p = __builtin_amdgcn_update_dpp(_s, _s, (ctrl), 0xf, 0xf, false);\
        x = fmaxf(x, __builtin_bit_cast(float, _p));                          \
    } while (0)
    DPP_STEP(0x111);  // row_shr:1
    DPP_STEP(0x112);  // row_shr:2
    DPP_STEP(0x114);  // row_shr:4
    DPP_STEP(0x118);  // row_shr:8
    DPP_STEP(0x142);  // row_bcast:15
    DPP_STEP(0x143);  // row_bcast:31
#undef DPP_STEP
    return __builtin_bit_cast(float,
        __builtin_amdgcn_readlane(__builtin_bit_cast(int, x), 63));
}

// =====================================================================
// Kernel 1 (register-resident, COLUMN-SLICED): 4 waves per (batch,chunk)
// block. M = C^T; columns of M evolve independently (M'[:,i]=D*E^T*M[:,i])
// so wave w owns the 16-column slice [16w,16w+16) entirely in registers:
//   Bt[rb] (rb=0..3) = M rows [16rb,16rb+16) x wave's cols = 8 VGPRs.
// Step: for mb: acc[mb] = sum_kb A(mb,kb) x Bt[kb]  (16 MFMAs, 4 indep
// chains of depth 4), then row-scale cs*descale (f32) + RNE f16 back
// into Bt. mfma_f32_16x16x16f16's D-layout == B-layout (verified round
// 8, absmax 0) -> zero data movement between steps.
//  vs round 8 (68 VGPR alloc => spill, 1 wave/SIMD => exposed latency):
//  - per-wave live state ~90 VGPR < 128 cap => no spill
//    (__launch_bounds__(256,4): 16 waves/CU resident).
//  - 4 waves/SIMD hide MFMA/LDS latency.
//  - renorm per-wave (per-16-C-rows), delayed 2 steps (exact pow2, D
//    compensates); combine absorbs via Dq[lane>>4] (round-6-verified).
// =====================================================================
template<int NCHT, int CHLT>
__global__ __launch_bounds__(256, 4)
void crf_chunk(const float* __restrict__ feats, const int* __restrict__ mask,
               const float* __restrict__ trans, f16_t* __restrict__ wsCt,
               float* __restrict__ wsD) {
    const int c    = blockIdx.x;          // chunk
    const int b    = blockIdx.y;          // batch
    const int tid  = threadIdx.x;
    const int w    = tid >> 6;            // wave = column-slice owner
    const int lane = tid & 63;
    const int l15  = lane & 15;
    const int q    = lane >> 4;

    __shared__ float sF[CHLT][64];        // 2^(f_t*log2e) per step / M-row
    __shared__ f16_t Ml[64 * 72];         // epilogue transpose, 144 B rows (16B-aligned)

    const int t0  = c * CHLT + 1;
    const int nst = (NS - t0 < CHLT) ? (NS - t0) : CHLT;

    // ---- A-const: E^T tiles. A(mb,kb) elem j = E[16kb+4q+j][16mb+l15]
    f16x4 Afrag[4][4];
    #pragma unroll
    for (int mb = 0; mb < 4; mb++)
        #pragma unroll
        for (int kb = 0; kb < 4; kb++) {
            f16x4 v;
            #pragma unroll
            for (int j = 0; j < 4; j++) {
                const int kk = 16 * kb + 4 * q + j;   // row of E
                const int mm = 16 * mb + l15;         // col of E
                float x = 0.f;
                if (kk < T && mm < T) x = fexp2(fmaf(trans[kk * T + mm], LOG2E, -S_E));
                v[j] = (f16_t)x;
            }
            Afrag[mb][kb] = v;
        }

    // ---- preload sF (exp2 once); 4 waves stripe the rows
    for (int r = w; r < CHLT; r += 4) {
        int tl = t0 + r; tl = tl < NS ? tl : NS - 1;
        float fv = (lane < T && r < nst) ? feats[((size_t)b * NS + tl) * T + lane] : 0.f;
        sF[r][lane] = (lane < T && r < nst) ? fexp2(fv * LOG2E) : 0.f;
    }

    // ---- mask bitmap (one ballot; per-step test is SALU)
    unsigned long long bm;
    {
        int tl = t0 + lane; tl = tl < NS ? tl : NS - 1;
        int mv = (lane < nst) ? mask[b * NS + tl] : 0;
        bm = __ballot(mv != 0);
    }
    __syncthreads();                      // sF visible to all waves

    // ---- init wave's slice of M = I: tile rb is I-block (rb, w)
    f16x4 Bt[4];
    #pragma unroll
    for (int rb = 0; rb < 4; rb++) {
        f16x4 v;
        #pragma unroll
        for (int j = 0; j < 4; j++)
            v[j] = (f16_t)((rb == w && 4 * q + j == l15) ? 1.f : 0.f);
        Bt[rb] = v;
    }

    float D  = 0.f;
    float m1 = 1.f, m2 = 1.f;             // wave max from s-1, s-2 (delayed renorm)

    for (int s = 0; s < nst; s++) {
        if ((bm >> s) & 1ull) {
            // descale from the max TWO doit-steps back (exact pow2; D compensates)
            int ebits = (int)((__float_as_uint(m2) >> 23) & 255) - 127;
            ebits = ebits > 14 ? 14 : (ebits < -14 ? -14 : ebits);
            const float descale = __uint_as_float((unsigned)(127 - ebits) << 23);
            D += (float)ebits + S_E;

            // 16 MFMAs: 4 independent depth-4 chains
            f32x4 acc[4];
            #pragma unroll
            for (int mb = 0; mb < 4; mb++) acc[mb] = (f32x4){0.f, 0.f, 0.f, 0.f};
            #pragma unroll
            for (int kb = 0; kb < 4; kb++)
                #pragma unroll
                for (int mb = 0; mb < 4; mb++)
                    acc[mb] = __builtin_amdgcn_mfma_f32_16x16x16f16(
                        Afrag[mb][kb], Bt[kb], acc[mb], 0, 0, 0);

            // row scales (M-row = tag row 16mb+4q+r), f32, then RNE f16
            float wm = 0.f;
            #pragma unroll
            for (int mb = 0; mb < 4; mb++) {
                f32x4 cs = *(const f32x4*)&sF[s][16 * mb + 4 * q];
                float v0 = acc[mb][0] * cs[0] * descale;
                float v1 = acc[mb][1] * cs[1] * descale;
                float v2 = acc[mb][2] * cs[2] * descale;
                float v3 = acc[mb][3] * cs[3] * descale;
                wm = fmaxf(wm, fmaxf(fmaxf(v0, v1), fmaxf(v2, v3)));
                f16x4 hv;
                hv[0] = (f16_t)v0; hv[1] = (f16_t)v1;   // RNE, matches prior rounds
                hv[2] = (f16_t)v2; hv[3] = (f16_t)v3;
                Bt[mb] = hv;       // D-layout == B-layout: feeds next step directly
            }

            m2 = m1;
            m1 = wave_fmax_dpp(wm);        // consumed two steps later
        }
    }

    // ---- epilogue: waves dump tiles -> barrier -> coalesced store
    {
        const int P2 = 72;
        #pragma unroll
        for (int rb = 0; rb < 4; rb++) {
            f16x4 v = Bt[rb];
            #pragma unroll
            for (int r = 0; r < 4; r++)
                Ml[(16 * rb + 4 * q + r) * P2 + 16 * w + l15] = v[r];
        }
        __syncthreads();
        // wsCt row j = M row j = column j of C (combine lane j's layout)
        const int row = tid >> 2;          // 0..63
        const int seg = tid & 3;           // 32 B segment
        const f16_t* src = &Ml[row * P2 + seg * 16];
        f16_t* dst = wsCt + ((size_t)(b * NCHT + c)) * 4096 + row * 64 + seg * 16;
        ((int4*)dst)[0] = *(const int4*)&src[0];
        ((int4*)dst)[1] = *(const int4*)&src[8];
    }
    if (lane == 0) wsD[(b * NCHT + c) * 4 + w] = D;   // per-wave (per-16-C-rows) shift
}

// =====================================================================
// Kernel 2 (round-6-verified structure): 2 waves per batch. Wave 0:
// part-chain over NCHT chunk matrices (lane j holds column j of C,
// contiguous 128 B, prefetched one chunk ahead; true-max shift via DPP;
// packed-f16 dot2). Wave 1: gold score concurrently. Per-16-row-block
// shift Dq[lane>>4] absorbs kernel 1's per-wave renorm.
// =====================================================================
template<int NCHT>
__global__ __launch_bounds__(128, 1)
void crf_combine(const float* __restrict__ feats, const int* __restrict__ mask,
                 const int* __restrict__ tags, const float* __restrict__ trans,
                 const f16_t* __restrict__ wsCt, const float* __restrict__ wsD,
                 float* __restrict__ out) {
    const int b    = blockIdx.x;
    const int tid  = threadIdx.x;
    const int wv   = tid >> 6;
    const int lane = tid & 63;

    __shared__ float sGold;
    float fwd = 0.f;

    if (wv == 1) {
        float gsum = 0.f;
        int   lcnt = 0;
        for (int s = lane; s < NS; s += 64) {
            int   m  = mask[b * NS + s];
            int   tg = tags[b * NS + s];
            int   pv = (s == 0) ? START_TAG : tags[b * NS + s - 1];
            float e  = feats[((size_t)b * NS + s) * T + tg];
            float tr = trans[pv * T + tg];
            if (m) { gsum += e + tr; lcnt += 1; }
        }
        #pragma unroll
        for (int off = 32; off > 0; off >>= 1) {
            gsum += __shfl_down(gsum, off, 64);
            lcnt += __shfl_down(lcnt, off, 64);
        }
        if (lane == 0) sGold = gsum + trans[tags[b * NS + lcnt - 1] * T + STOP_TAG];
    } else {
        float part = (lane < T)
            ? (feats[(size_t)b * NS * T + lane] + trans[START_TAG * T + lane]) * LOG2E
            : NEG_BIG;

        float Dq[NCHT];
        #pragma unroll
        for (int cc = 0; cc < NCHT; cc++)
            Dq[cc] = wsD[(b * NCHT + cc) * 4 + (lane >> 4)];

        int cur[32], nxt[32];
        {
            const f16_t* src = wsCt + (size_t)b * NCHT * 4096 + lane * 64;
            #pragma unroll
            for (int kk = 0; kk < 8; kk++)
                *(int4*)&cur[4 * kk] = ((const int4*)src)[kk];
        }

        #pragma unroll
        for (int cc = 0; cc < NCHT; cc++) {
            if (cc + 1 < NCHT) {
                const f16_t* src = wsCt + (size_t)(b * NCHT + cc + 1) * 4096 + lane * 64;
                #pragma unroll
                for (int kk = 0; kk < 8; kk++)
                    *(int4*)&nxt[4 * kk] = ((const int4*)src)[kk];
            }

            float tmp = part + Dq[cc];
            float sft = wave_fmax_dpp(tmp);
            float ex  = fexp2(tmp - sft);
            float exo = __shfl_xor(ex, 1, 64);
            f16x2 pk  = pack_h2(ex, exo);

            float a0 = 0.f, a1 = 0.f, a2 = 0.f, a3 = 0.f;
            #pragma unroll
            for (int k = 0; k < 25; k += 4) {
                a0 = __builtin_amdgcn_fdot2(bcast_h2(pk, 2 * k), __builtin_bit_cast(f16x2, cur[k]), a0, false);
                if (k + 1 < 25) a1 = __builtin_amdgcn_fdot2(bcast_h2(pk, 2 * (k + 1)), __builtin_bit_cast(f16x2, cur[k + 1]), a1, false);
                if (k + 2 < 25) a2 = __builtin_amdgcn_fdot2(bcast_h2(pk, 2 * (k + 2)), __builtin_bit_cast(f16x2, cur[k + 2]), a2, false);
                if (k + 3 < 25) a3 = __builtin_amdgcn_fdot2(bcast_h2(pk, 2 * (k + 3)), __builtin_bit_cast(f16x2, cur[k + 3]), a3, false);
            }
            part = sft + flog2((a0 + a1) + (a2 + a3));

            if (cc + 1 < NCHT) {
                #pragma unroll
                for (int kk = 0; kk < 32; kk++) cur[kk] = nxt[kk];
            }
        }

        float v = (lane < T) ? part + trans[lane * T + STOP_TAG] * LOG2E : NEG_BIG;
        float mx = wave_fmax_dpp(v);
        float ee = (lane < T) ? fexp2(v - mx) : 0.f;
        #pragma unroll
        for (int off = 32; off > 0; off >>= 1) ee += __shfl_xor(ee, off, 64);
        fwd = (mx + flog2(ee)) * LN2F;
    }

    __syncthreads();
    if (tid == 0) atomicAdd(out, fwd - sGold);
}

extern "C" void kernel_launch(void* const* d_in, const int* in_sizes, int n_in,
                              void* d_out, int out_size, void* d_ws, size_t ws_size,
                              hipStream_t stream) {
    const float* feats = (const float*)d_in[0];
    const int*   mask  = (const int*)d_in[1];
    const int*   tags  = (const int*)d_in[2];
    const float* trans = (const float*)d_in[3];
    float* out = (float*)d_out;

    (void)hipMemsetAsync(out, 0, sizeof(float) * out_size, stream);

    const size_t matBytes16 = (size_t)NB * 16 * 4096 * sizeof(f16_t);
    const size_t need16     = matBytes16 + (size_t)NB * 16 * 4 * sizeof(float);

    if (ws_size >= need16) {
        // preferred: 16 chunks x 32 steps, 1024 blocks x 4 waves = 16 waves/CU
        f16_t* wsCt = (f16_t*)d_ws;
        float* wsD  = (float*)((char*)d_ws + matBytes16);
        crf_chunk<16, 32><<<dim3(16, NB), 256, 0, stream>>>(feats, mask, trans, wsCt, wsD);
        crf_combine<16><<<NB, 128, 0, stream>>>(feats, mask, tags, trans, wsCt, wsD, out);
    } else {
        // fallback: 8 chunks x 64 steps (fits 4.2 MB)
        const size_t matBytes8 = (size_t)NB * 8 * 4096 * sizeof(f16_t);
        f16_t* wsCt = (f16_t*)d_ws;
        float* wsD  = (float*)((char*)d_ws + matBytes8);
        crf_chunk<8, 64><<<dim3(8, NB), 256, 0, stream>>>(feats, mask, trans, wsCt, wsD);
        crf_combine<8><<<NB, 128, 0, stream>>>(feats, mask, tags, trans, wsCt, wsD, out);
    }
}